// Round 1
// baseline (1125.005 us; speedup 1.0000x reference)
//
#include <hip/hip_runtime.h>

#define HN 4
#define VDIM 2
#define BDIM 2048
#define C1N 1024
#define C2N 2048
#define NDIM 4096
#define EPSV 1e-7f
#define ITEMP (1.0f/0.05f)

typedef float f32x4 __attribute__((ext_vector_type(4)));
typedef short short8 __attribute__((ext_vector_type(8)));

__device__ __forceinline__ unsigned short f2bf(float f){
    unsigned u = __float_as_uint(f);
    unsigned r = (u + 0x7FFFu + ((u >> 16) & 1u)) >> 16;
    return (unsigned short)r;
}
__device__ __forceinline__ float bf2f(unsigned short s){
    return __uint_as_float(((unsigned)s) << 16);
}

// ---------------- zero init ----------------
__global__ void kzero(float* p, int n){
    int i = blockIdx.x * blockDim.x + threadIdx.x;
    if (i < n) p[i] = 0.f;
}

// ---------------- pass 1: row softmax stats (max, 1/sum) ----------------
template<int C>
__global__ __launch_bounds__(256) void kstats(const float* __restrict__ x,
                                              float2* __restrict__ st){
    const int bid = blockIdx.x;            // h*NDIM + n
    const int h = bid >> 12;
    const int n = bid & (NDIM - 1);
    const int v = n >> 11, b = n & (BDIM - 1);
    const float4* row = (const float4*)(x + ((size_t)((v*HN + h)*BDIM + b)) * C);
    const int t = threadIdx.x;
    constexpr int NV = C / 1024;
    float4 a[NV];
    float m = -3.4e38f;
#pragma unroll
    for (int i = 0; i < NV; ++i){
        a[i] = row[t + i*256];
        m = fmaxf(m, fmaxf(fmaxf(a[i].x, a[i].y), fmaxf(a[i].z, a[i].w)));
    }
    __shared__ float red[4];
    for (int o = 32; o > 0; o >>= 1) m = fmaxf(m, __shfl_xor(m, o));
    if ((t & 63) == 0) red[t >> 6] = m;
    __syncthreads();
    m = fmaxf(fmaxf(red[0], red[1]), fmaxf(red[2], red[3]));
    __syncthreads();
    float s = 0.f;
#pragma unroll
    for (int i = 0; i < NV; ++i){
        s += expf((a[i].x - m)*ITEMP) + expf((a[i].y - m)*ITEMP)
           + expf((a[i].z - m)*ITEMP) + expf((a[i].w - m)*ITEMP);
    }
    for (int o = 32; o > 0; o >>= 1) s += __shfl_xor(s, o);
    if ((t & 63) == 0) red[t >> 6] = s;
    __syncthreads();
    if (t == 0){
        float tot = red[0] + red[1] + red[2] + red[3];
        st[bid] = make_float2(m, 1.f / tot);
    }
}

// ---- pass 2: normalize + split bf16 hi/lo + transpose to (h,C,N) + colsum ----
template<int C>
__global__ __launch_bounds__(256) void knt(const float* __restrict__ x,
                                           const float2* __restrict__ st,
                                           unsigned short* __restrict__ thi,
                                           unsigned short* __restrict__ tlo,
                                           float* __restrict__ psum){
    __shared__ unsigned short sh[64][68];
    __shared__ unsigned short sl[64][68];
    __shared__ float2 sst[64];
    const int tid = threadIdx.x;
    const int h  = blockIdx.z;
    const int c0 = blockIdx.x * 64;   // over C
    const int r0 = blockIdx.y * 64;   // over N
    if (tid < 64) sst[tid] = st[h*NDIM + r0 + tid];
    __syncthreads();
    const int col = (tid & 15) * 4;
#pragma unroll
    for (int i = 0; i < 4; ++i){
        const int rr = (tid >> 4) + i*16;
        const int n = r0 + rr;
        const int v = n >> 11, b = n & (BDIM - 1);
        float4 xv = *(const float4*)(x + ((size_t)((v*HN + h)*BDIM + b))*C + c0 + col);
        const float m = sst[rr].x, inv = sst[rr].y;
        float vals[4] = {xv.x, xv.y, xv.z, xv.w};
#pragma unroll
        for (int e = 0; e < 4; ++e){
            float val = expf((vals[e] - m)*ITEMP) * inv;
            unsigned short hb = f2bf(val);
            float lo = val - bf2f(hb);
            sh[rr][col + e] = hb;
            sl[rr][col + e] = f2bf(lo);
        }
    }
    __syncthreads();
    if (tid < 64){
        float s = 0.f;
#pragma unroll 8
        for (int r = 0; r < 64; ++r) s += bf2f(sh[r][tid]) + bf2f(sl[r][tid]);
        atomicAdd(&psum[h*C + c0 + tid], s);
    }
    const int rb = (tid & 15) * 4;
#pragma unroll
    for (int i = 0; i < 4; ++i){
        const int cc = (tid >> 4) + i*16;
        ushort4 vh, vl;
        vh.x = sh[rb+0][cc]; vh.y = sh[rb+1][cc]; vh.z = sh[rb+2][cc]; vh.w = sh[rb+3][cc];
        vl.x = sl[rb+0][cc]; vl.y = sl[rb+1][cc]; vl.z = sl[rb+2][cc]; vl.w = sl[rb+3][cc];
        size_t o = ((size_t)(h*C + c0 + cc))*NDIM + r0 + rb;
        *(ushort4*)(thi + o) = vh;
        *(ushort4*)(tlo + o) = vl;
    }
}

// ---------------- small: log of clamped p_seen ----------------
__global__ void klogps(const float* __restrict__ psum, float* __restrict__ lps){
    int i = blockIdx.x * 256 + threadIdx.x;
    if (i < HN*C1N) lps[i] = logf(fmaxf(psum[i] * (1.f/NDIM), EPSV));
}

// ---------------- entropy term from p_unseen ----------------
__global__ __launch_bounds__(256) void ks2(const float* __restrict__ psum_u, float* S){
    int i = blockIdx.x * 256 + threadIdx.x;
    float t = 0.f;
    if (i < HN*C2N){
        float pu = fmaxf(psum_u[i] * (1.f/NDIM), EPSV);
        t = pu * logf(pu);
    }
    for (int o = 32; o > 0; o >>= 1) t += __shfl_xor(t, o);
    __shared__ float red[4];
    if ((threadIdx.x & 63) == 0) red[threadIdx.x >> 6] = t;
    __syncthreads();
    if (threadIdx.x == 0) atomicAdd(&S[1], red[0]+red[1]+red[2]+red[3]);
}

// ------ GEMM: pj[h][c][k] = (1/N) sum_n xu[h][n][c]*xs[h][n][k], split-bf16 ------
// A = xu_t (h, C2, N) K-contig, B = xs_t (h, C1, N) K-contig. 128x128 tile, BK=32.
__global__ __launch_bounds__(256) void kgemm(const unsigned short* __restrict__ Ahi,
                                             const unsigned short* __restrict__ Alo,
                                             const unsigned short* __restrict__ Bhi,
                                             const unsigned short* __restrict__ Blo,
                                             float* __restrict__ pj){
    __shared__ unsigned short Ah[128][40];
    __shared__ unsigned short Al[128][40];
    __shared__ unsigned short Bh[128][40];
    __shared__ unsigned short Bl[128][40];
    const int tid = threadIdx.x;
    const int h  = blockIdx.z;
    const int k0 = blockIdx.x * 128;   // over C1
    const int c0 = blockIdx.y * 128;   // over C2
    const int lane = tid & 63, wid = tid >> 6;
    const int wr = wid >> 1, wc = wid & 1;
    f32x4 acc[4][4];
#pragma unroll
    for (int m = 0; m < 4; ++m)
#pragma unroll
        for (int nn = 0; nn < 4; ++nn) acc[m][nn] = (f32x4){0.f, 0.f, 0.f, 0.f};

    const int lr = lane & 15, lk = (lane >> 4) * 8;

    for (int t = 0; t < NDIM/32; ++t){
        const int n0 = t * 32;
        uint4 ra[2], rb[2], rc[2], rd[2];
#pragma unroll
        for (int i = 0; i < 2; ++i){
            int q = tid + i*256; int row = q >> 2; int seg = q & 3;
            size_t offA = ((size_t)(h*C2N + c0 + row))*NDIM + n0 + seg*8;
            size_t offB = ((size_t)(h*C1N + k0 + row))*NDIM + n0 + seg*8;
            ra[i] = *(const uint4*)(Ahi + offA);
            rb[i] = *(const uint4*)(Alo + offA);
            rc[i] = *(const uint4*)(Bhi + offB);
            rd[i] = *(const uint4*)(Blo + offB);
        }
        __syncthreads();
#pragma unroll
        for (int i = 0; i < 2; ++i){
            int q = tid + i*256; int row = q >> 2; int seg = q & 3;
            *(uint4*)&Ah[row][seg*8] = ra[i];
            *(uint4*)&Al[row][seg*8] = rb[i];
            *(uint4*)&Bh[row][seg*8] = rc[i];
            *(uint4*)&Bl[row][seg*8] = rd[i];
        }
        __syncthreads();
        short8 ah[4], al[4];
#pragma unroll
        for (int m = 0; m < 4; ++m){
            ah[m] = *reinterpret_cast<const short8*>(&Ah[wr*64 + m*16 + lr][lk]);
            al[m] = *reinterpret_cast<const short8*>(&Al[wr*64 + m*16 + lr][lk]);
        }
#pragma unroll
        for (int nn = 0; nn < 4; ++nn){
            short8 bh = *reinterpret_cast<const short8*>(&Bh[wc*64 + nn*16 + lr][lk]);
            short8 bl = *reinterpret_cast<const short8*>(&Bl[wc*64 + nn*16 + lr][lk]);
#pragma unroll
            for (int m = 0; m < 4; ++m){
                acc[m][nn] = __builtin_amdgcn_mfma_f32_16x16x32_bf16(ah[m], bh, acc[m][nn], 0, 0, 0);
                acc[m][nn] = __builtin_amdgcn_mfma_f32_16x16x32_bf16(ah[m], bl, acc[m][nn], 0, 0, 0);
                acc[m][nn] = __builtin_amdgcn_mfma_f32_16x16x32_bf16(al[m], bh, acc[m][nn], 0, 0, 0);
            }
        }
    }
    const float sc = 1.f / NDIM;
#pragma unroll
    for (int m = 0; m < 4; ++m)
#pragma unroll
        for (int nn = 0; nn < 4; ++nn)
#pragma unroll
            for (int r = 0; r < 4; ++r){
                int c = c0 + wr*64 + m*16 + (lane >> 4)*4 + r;
                int k = k0 + wc*64 + nn*16 + lr;
                pj[((size_t)(h*C2N + c))*C1N + k] = acc[m][nn][r] * sc;
            }
}

// ---------------- final: sum pj*(log pj - log ps) ----------------
__global__ __launch_bounds__(256) void kfinal(const float* __restrict__ pj,
                                              const float* __restrict__ lps,
                                              float* S){
    float acc = 0.f;
    const int total = HN*C2N*C1N;
    const int stride = gridDim.x * 256;
    for (int i = blockIdx.x*256 + threadIdx.x; i < total; i += stride){
        float t = fmaxf(pj[i], EPSV);
        int k = i & (C1N - 1);
        int h = i >> 21;
        acc += t * (logf(t) - lps[h*C1N + k]);
    }
    for (int o = 32; o > 0; o >>= 1) acc += __shfl_xor(acc, o);
    __shared__ float red[4];
    if ((threadIdx.x & 63) == 0) red[threadIdx.x >> 6] = acc;
    __syncthreads();
    if (threadIdx.x == 0) atomicAdd(&S[0], red[0]+red[1]+red[2]+red[3]);
}

__global__ void kfinish(const float* S, float* out){
    if (threadIdx.x == 0) out[0] = 0.25f * (S[1] - S[0]);
}

// ---------------- workspace layout (bytes) ----------------
#define XS_HI_OFF   0ull
#define XS_LO_OFF   33554432ull
#define XU_HI_OFF   67108864ull
#define XU_LO_OFF   134217728ull
#define PJ_OFF      201326592ull
#define STATS_S_OFF 234881024ull
#define STATS_U_OFF 235012096ull
#define PSUM_S_OFF  235143168ull
#define PSUM_U_OFF  235159552ull
#define LPS_OFF     235192320ull
#define SACC_OFF    235208704ull

extern "C" void kernel_launch(void* const* d_in, const int* in_sizes, int n_in,
                              void* d_out, int out_size, void* d_ws, size_t ws_size,
                              hipStream_t stream){
    const float* x_seen   = (const float*)d_in[0];
    const float* x_unseen = (const float*)d_in[1];
    char* ws = (char*)d_ws;

    unsigned short* xs_hi = (unsigned short*)(ws + XS_HI_OFF);
    unsigned short* xs_lo = (unsigned short*)(ws + XS_LO_OFF);
    unsigned short* xu_hi = (unsigned short*)(ws + XU_HI_OFF);
    unsigned short* xu_lo = (unsigned short*)(ws + XU_LO_OFF);
    float*  pj      = (float*)(ws + PJ_OFF);
    float2* stats_s = (float2*)(ws + STATS_S_OFF);
    float2* stats_u = (float2*)(ws + STATS_U_OFF);
    float*  psum_s  = (float*)(ws + PSUM_S_OFF);
    float*  psum_u  = (float*)(ws + PSUM_U_OFF);
    float*  lps     = (float*)(ws + LPS_OFF);
    float*  Sacc    = (float*)(ws + SACC_OFF);
    float*  out     = (float*)d_out;

    // zero psum_s + psum_u + lps + S (contiguous): 4096+8192+4096+2 floats
    kzero<<<65, 256, 0, stream>>>(psum_s, 16386);

    kstats<C1N><<<HN*NDIM, 256, 0, stream>>>(x_seen, stats_s);
    kstats<C2N><<<HN*NDIM, 256, 0, stream>>>(x_unseen, stats_u);

    knt<C1N><<<dim3(C1N/64, NDIM/64, HN), 256, 0, stream>>>(x_seen, stats_s, xs_hi, xs_lo, psum_s);
    knt<C2N><<<dim3(C2N/64, NDIM/64, HN), 256, 0, stream>>>(x_unseen, stats_u, xu_hi, xu_lo, psum_u);

    klogps<<<16, 256, 0, stream>>>(psum_s, lps);
    ks2<<<32, 256, 0, stream>>>(psum_u, Sacc);

    kgemm<<<dim3(C1N/128, C2N/128, HN), 256, 0, stream>>>(xu_hi, xu_lo, xs_hi, xs_lo, pj);

    kfinal<<<2048, 256, 0, stream>>>(pj, lps, Sacc);
    kfinish<<<1, 64, 0, stream>>>(Sacc, out);
}

// Round 2
// 612.430 us; speedup vs baseline: 1.8370x; 1.8370x over previous
//
#include <hip/hip_runtime.h>

#define HN 4
#define VDIM 2
#define BDIM 2048
#define C1N 1024
#define C2N 2048
#define NDIM 4096
#define EPSV 1e-7f
#define ITEMP (1.0f/0.05f)
#define KSPLIT 2

typedef float f32x4 __attribute__((ext_vector_type(4)));
typedef short short8 __attribute__((ext_vector_type(8)));

__device__ __forceinline__ unsigned short f2bf(float f){
    unsigned u = __float_as_uint(f);
    unsigned r = (u + 0x7FFFu + ((u >> 16) & 1u)) >> 16;
    return (unsigned short)r;
}
__device__ __forceinline__ float bf2f(unsigned short s){
    return __uint_as_float(((unsigned)s) << 16);
}

// async global -> LDS, 16B per lane (m97 pattern; LDS dest must be linear in lane)
__device__ __forceinline__ void gl16(const void* g, void* l){
    __builtin_amdgcn_global_load_lds(
        (const __attribute__((address_space(1))) unsigned int*)g,
        (__attribute__((address_space(3))) unsigned int*)l, 16, 0, 0);
}

// ---------------- zero init (pj .. Sacc region) ----------------
__global__ void kzero(float* p, int n){
    int i = blockIdx.x * blockDim.x + threadIdx.x;
    if (i < n) p[i] = 0.f;
}

// ---------------- pass 1: row softmax stats (max, 1/sum) ----------------
template<int C>
__global__ __launch_bounds__(256) void kstats(const float* __restrict__ x,
                                              float2* __restrict__ st){
    const int bid = blockIdx.x;            // h*NDIM + n
    const int h = bid >> 12;
    const int n = bid & (NDIM - 1);
    const int v = n >> 11, b = n & (BDIM - 1);
    const float4* row = (const float4*)(x + ((size_t)((v*HN + h)*BDIM + b)) * C);
    const int t = threadIdx.x;
    constexpr int NV = C / 1024;
    float4 a[NV];
    float m = -3.4e38f;
#pragma unroll
    for (int i = 0; i < NV; ++i){
        a[i] = row[t + i*256];
        m = fmaxf(m, fmaxf(fmaxf(a[i].x, a[i].y), fmaxf(a[i].z, a[i].w)));
    }
    __shared__ float red[4];
    for (int o = 32; o > 0; o >>= 1) m = fmaxf(m, __shfl_xor(m, o));
    if ((t & 63) == 0) red[t >> 6] = m;
    __syncthreads();
    m = fmaxf(fmaxf(red[0], red[1]), fmaxf(red[2], red[3]));
    __syncthreads();
    float s = 0.f;
#pragma unroll
    for (int i = 0; i < NV; ++i){
        s += expf((a[i].x - m)*ITEMP) + expf((a[i].y - m)*ITEMP)
           + expf((a[i].z - m)*ITEMP) + expf((a[i].w - m)*ITEMP);
    }
    for (int o = 32; o > 0; o >>= 1) s += __shfl_xor(s, o);
    if ((t & 63) == 0) red[t >> 6] = s;
    __syncthreads();
    if (t == 0){
        float tot = red[0] + red[1] + red[2] + red[3];
        st[bid] = make_float2(m, 1.f / tot);
    }
}

// ---- pass 2: normalize + split bf16 hi/lo + transpose to (h,C,N) + colsum ----
template<int C>
__global__ __launch_bounds__(256) void knt(const float* __restrict__ x,
                                           const float2* __restrict__ st,
                                           unsigned short* __restrict__ thi,
                                           unsigned short* __restrict__ tlo,
                                           float* __restrict__ psum){
    __shared__ unsigned short sh[64][68];
    __shared__ unsigned short sl[64][68];
    __shared__ float2 sst[64];
    const int tid = threadIdx.x;
    const int h  = blockIdx.z;
    const int c0 = blockIdx.x * 64;   // over C
    const int r0 = blockIdx.y * 64;   // over N
    if (tid < 64) sst[tid] = st[h*NDIM + r0 + tid];
    __syncthreads();
    const int col = (tid & 15) * 4;
#pragma unroll
    for (int i = 0; i < 4; ++i){
        const int rr = (tid >> 4) + i*16;
        const int n = r0 + rr;
        const int v = n >> 11, b = n & (BDIM - 1);
        float4 xv = *(const float4*)(x + ((size_t)((v*HN + h)*BDIM + b))*C + c0 + col);
        const float m = sst[rr].x, inv = sst[rr].y;
        float vals[4] = {xv.x, xv.y, xv.z, xv.w};
#pragma unroll
        for (int e = 0; e < 4; ++e){
            float val = expf((vals[e] - m)*ITEMP) * inv;
            unsigned short hb = f2bf(val);
            float lo = val - bf2f(hb);
            sh[rr][col + e] = hb;
            sl[rr][col + e] = f2bf(lo);
        }
    }
    __syncthreads();
    if (tid < 64){
        float s = 0.f;
#pragma unroll 8
        for (int r = 0; r < 64; ++r) s += bf2f(sh[r][tid]) + bf2f(sl[r][tid]);
        atomicAdd(&psum[h*C + c0 + tid], s);
    }
    const int rb = (tid & 15) * 4;
#pragma unroll
    for (int i = 0; i < 4; ++i){
        const int cc = (tid >> 4) + i*16;
        ushort4 vh, vl;
        vh.x = sh[rb+0][cc]; vh.y = sh[rb+1][cc]; vh.z = sh[rb+2][cc]; vh.w = sh[rb+3][cc];
        vl.x = sl[rb+0][cc]; vl.y = sl[rb+1][cc]; vl.z = sl[rb+2][cc]; vl.w = sl[rb+3][cc];
        size_t o = ((size_t)(h*C + c0 + cc))*NDIM + r0 + rb;
        *(ushort4*)(thi + o) = vh;
        *(ushort4*)(tlo + o) = vl;
    }
}

// ---------------- merged: log(p_seen) table + p_unseen entropy ----------------
__global__ __launch_bounds__(256) void kls(const float* __restrict__ psum_s,
                                           const float* __restrict__ psum_u,
                                           float* __restrict__ lps, float* S){
    int i = blockIdx.x * 256 + threadIdx.x;
    if (i < HN*C1N) lps[i] = logf(fmaxf(psum_s[i] * (1.f/NDIM), EPSV));
    float t = 0.f;
    if (i < HN*C2N){
        float pu = fmaxf(psum_u[i] * (1.f/NDIM), EPSV);
        t = pu * logf(pu);
    }
    for (int o = 32; o > 0; o >>= 1) t += __shfl_xor(t, o);
    __shared__ float red[4];
    if ((threadIdx.x & 63) == 0) red[threadIdx.x >> 6] = t;
    __syncthreads();
    if (threadIdx.x == 0) atomicAdd(&S[1], red[0]+red[1]+red[2]+red[3]);
}

// ------ GEMM (m97 structure): pj[h][c][k] += sum_n xu[h][n][c]*xs[h][n][k] ------
// A = xu_t (h, C2, N) K-contig, B = xs_t (h, C1, N) K-contig.
// 128x128 tile, BK=32, 4 waves (2x2), split-K=2 via fp32 atomics. Linear LDS,
// global_load_lds width-16 staging, 2 barriers per K-step.
__global__ __launch_bounds__(256) void kgemm(const unsigned short* __restrict__ Ahi,
                                             const unsigned short* __restrict__ Alo,
                                             const unsigned short* __restrict__ Bhi,
                                             const unsigned short* __restrict__ Blo,
                                             float* __restrict__ pj){
    __shared__ unsigned short lds[4*128*32];           // 32 KB, 4 linear planes
    unsigned short* Ah = lds;
    unsigned short* Al = lds + 4096;
    unsigned short* Bh = lds + 8192;
    unsigned short* Bl = lds + 12288;
    const int tid = threadIdx.x;
    const int z = blockIdx.z;
    const int h = z >> 1, ks = z & 1;
    const int k0 = blockIdx.x * 128;   // over C1
    const int c0 = blockIdx.y * 128;   // over C2
    const int lane = tid & 63, wid = tid >> 6;
    const int wr = wid >> 1, wc = wid & 1;
    const int lr = lane & 15, lk = (lane >> 4) * 8;

    f32x4 acc[4][4];
#pragma unroll
    for (int m = 0; m < 4; ++m)
#pragma unroll
        for (int nn = 0; nn < 4; ++nn) acc[m][nn] = (f32x4){0.f, 0.f, 0.f, 0.f};

    const size_t baseA = (size_t)(h*C2N + c0);
    const size_t baseB = (size_t)(h*C1N + k0);
    // staging chunk ids: ci = i*256 + tid; row = ci>>2; cu = (ci&3)*8
    const int row0 = tid >> 2,          cu0 = (tid & 3) * 8;
    const int row1 = (256 + tid) >> 2,  cu1 = (tid & 3) * 8;  // (256+tid)&3 == tid&3
    const int lo0 = tid * 8, lo1 = (256 + tid) * 8;

    for (int t = 0; t < 2048/32; ++t){
        const int n0 = ks*2048 + t*32;
        {
            size_t gA0 = (baseA + row0)*NDIM + n0 + cu0;
            size_t gB0 = (baseB + row0)*NDIM + n0 + cu0;
            size_t gA1 = (baseA + row1)*NDIM + n0 + cu1;
            size_t gB1 = (baseB + row1)*NDIM + n0 + cu1;
            gl16(Ahi + gA0, Ah + lo0);
            gl16(Alo + gA0, Al + lo0);
            gl16(Bhi + gB0, Bh + lo0);
            gl16(Blo + gB0, Bl + lo0);
            gl16(Ahi + gA1, Ah + lo1);
            gl16(Alo + gA1, Al + lo1);
            gl16(Bhi + gB1, Bh + lo1);
            gl16(Blo + gB1, Bl + lo1);
        }
        __syncthreads();   // compiler drains vmcnt before s_barrier
        short8 ah[4], al[4];
#pragma unroll
        for (int m = 0; m < 4; ++m){
            ah[m] = *reinterpret_cast<const short8*>(&Ah[(wr*64 + m*16 + lr)*32 + lk]);
            al[m] = *reinterpret_cast<const short8*>(&Al[(wr*64 + m*16 + lr)*32 + lk]);
        }
#pragma unroll
        for (int nn = 0; nn < 4; ++nn){
            short8 bh = *reinterpret_cast<const short8*>(&Bh[(wc*64 + nn*16 + lr)*32 + lk]);
            short8 bl = *reinterpret_cast<const short8*>(&Bl[(wc*64 + nn*16 + lr)*32 + lk]);
#pragma unroll
            for (int m = 0; m < 4; ++m){
                acc[m][nn] = __builtin_amdgcn_mfma_f32_16x16x32_bf16(ah[m], bh, acc[m][nn], 0, 0, 0);
                acc[m][nn] = __builtin_amdgcn_mfma_f32_16x16x32_bf16(ah[m], bl, acc[m][nn], 0, 0, 0);
                acc[m][nn] = __builtin_amdgcn_mfma_f32_16x16x32_bf16(al[m], bh, acc[m][nn], 0, 0, 0);
            }
        }
        __syncthreads();   // all waves done reading LDS before next stage overwrites
    }
    const int rr4 = (lane >> 4) * 4;
#pragma unroll
    for (int m = 0; m < 4; ++m)
#pragma unroll
        for (int nn = 0; nn < 4; ++nn)
#pragma unroll
            for (int r = 0; r < 4; ++r){
                int c = c0 + wr*64 + m*16 + rr4 + r;
                int k = k0 + wc*64 + nn*16 + lr;
                atomicAdd(&pj[((size_t)(h*C2N + c))*C1N + k], acc[m][nn][r]);
            }
}

// ---------------- final: sum pj*(log pj - log ps) ----------------
__global__ __launch_bounds__(256) void kfinal(const float* __restrict__ pj,
                                              const float* __restrict__ lps,
                                              float* S){
    float acc = 0.f;
    const int total = HN*C2N*C1N;
    const int stride = gridDim.x * 256;
    for (int i = blockIdx.x*256 + threadIdx.x; i < total; i += stride){
        float t = fmaxf(pj[i] * (1.f/NDIM), EPSV);
        int k = i & (C1N - 1);
        int h = i >> 21;
        acc += t * (logf(t) - lps[h*C1N + k]);
    }
    for (int o = 32; o > 0; o >>= 1) acc += __shfl_xor(acc, o);
    __shared__ float red[4];
    if ((threadIdx.x & 63) == 0) red[threadIdx.x >> 6] = acc;
    __syncthreads();
    if (threadIdx.x == 0) atomicAdd(&S[0], red[0]+red[1]+red[2]+red[3]);
}

__global__ void kfinish(const float* S, float* out){
    if (threadIdx.x == 0) out[0] = 0.25f * (S[1] - S[0]);
}

// ---------------- workspace layout (bytes) ----------------
#define XS_HI_OFF   0ull
#define XS_LO_OFF   33554432ull
#define XU_HI_OFF   67108864ull
#define XU_LO_OFF   134217728ull
#define PJ_OFF      201326592ull
#define STATS_S_OFF 234881024ull
#define STATS_U_OFF 235012096ull
#define PSUM_S_OFF  235143168ull
#define PSUM_U_OFF  235159552ull
#define LPS_OFF     235192320ull
#define SACC_OFF    235208704ull

extern "C" void kernel_launch(void* const* d_in, const int* in_sizes, int n_in,
                              void* d_out, int out_size, void* d_ws, size_t ws_size,
                              hipStream_t stream){
    const float* x_seen   = (const float*)d_in[0];
    const float* x_unseen = (const float*)d_in[1];
    char* ws = (char*)d_ws;

    unsigned short* xs_hi = (unsigned short*)(ws + XS_HI_OFF);
    unsigned short* xs_lo = (unsigned short*)(ws + XS_LO_OFF);
    unsigned short* xu_hi = (unsigned short*)(ws + XU_HI_OFF);
    unsigned short* xu_lo = (unsigned short*)(ws + XU_LO_OFF);
    float*  pj      = (float*)(ws + PJ_OFF);
    float2* stats_s = (float2*)(ws + STATS_S_OFF);
    float2* stats_u = (float2*)(ws + STATS_U_OFF);
    float*  psum_s  = (float*)(ws + PSUM_S_OFF);
    float*  psum_u  = (float*)(ws + PSUM_U_OFF);
    float*  lps     = (float*)(ws + LPS_OFF);
    float*  Sacc    = (float*)(ws + SACC_OFF);
    float*  out     = (float*)d_out;

    // zero pj (atomic split-K target) + psum_s/psum_u/lps/Sacc — one contiguous region
    const int nz = (int)((SACC_OFF + 8 - PJ_OFF) / 4);
    kzero<<<(nz + 255)/256, 256, 0, stream>>>(pj, nz);

    kstats<C1N><<<HN*NDIM, 256, 0, stream>>>(x_seen, stats_s);
    kstats<C2N><<<HN*NDIM, 256, 0, stream>>>(x_unseen, stats_u);

    knt<C1N><<<dim3(C1N/64, NDIM/64, HN), 256, 0, stream>>>(x_seen, stats_s, xs_hi, xs_lo, psum_s);
    knt<C2N><<<dim3(C2N/64, NDIM/64, HN), 256, 0, stream>>>(x_unseen, stats_u, xu_hi, xu_lo, psum_u);

    kls<<<32, 256, 0, stream>>>(psum_s, psum_u, lps, Sacc);

    kgemm<<<dim3(C1N/128, C2N/128, HN*KSPLIT), 256, 0, stream>>>(xu_hi, xu_lo, xs_hi, xs_lo, pj);

    kfinal<<<2048, 256, 0, stream>>>(pj, lps, Sacc);
    kfinish<<<1, 64, 0, stream>>>(Sacc, out);
}